// Round 3
// baseline (1702.576 us; speedup 1.0000x reference)
//
#include <hip/hip_runtime.h>
#include <cstdint>

#define NN 100000
#define NE 1600000

typedef __attribute__((ext_vector_type(8))) short bf16x8;
typedef __attribute__((ext_vector_type(4))) float f32x4;

static __device__ __forceinline__ short f2bf(float f) {
  union { float f; unsigned u; } v; v.f = f;
  unsigned r = (v.u + 0x7FFFu + ((v.u >> 16) & 1u)) >> 16;
  return (short)r;
}
static __device__ __forceinline__ float bf2f(unsigned short s) {
  union { unsigned u; float f; } v; v.u = ((unsigned)s) << 16;
  return v.f;
}

// ---------------- zero the degree array (no host memset in capture path) ----
__global__ void zero_k(int* __restrict__ p, int n) {
  int i = blockIdx.x * 256 + threadIdx.x;
  if (i < n) p[i] = 0;
}

// ---------------- weight pre-convert to MFMA fragment order ----------------
// W1f: [kb<32][nt<32][lane<64][j<8]  covering K=1024(pad from 1000), N=512
// W2f: [kb<16][nt<16][lane][j]       K=512, N=256
// Wgf: [kb<9 ][nt<8 ][lane][j]       K=288(pad from 266), N=128
__global__ void wconv_k(const float* __restrict__ W1, const float* __restrict__ W2,
                        const float* __restrict__ Wg,
                        bf16x8* __restrict__ W1f, bf16x8* __restrict__ W2f,
                        bf16x8* __restrict__ Wgf) {
  int id = blockIdx.x * 256 + threadIdx.x;
  const int n1 = 32 * 32 * 64, n2 = 16 * 16 * 64, n3 = 9 * 8 * 64;
  if (id < n1) {
    int lane = id & 63, nt = (id >> 6) & 31, kb = id >> 11;
    int q = lane >> 4, ln = lane & 15, n = nt * 16 + ln;
    bf16x8 o;
#pragma unroll
    for (int j = 0; j < 8; ++j) {
      int k = kb * 32 + q * 8 + j;
      o[j] = (k < 1000) ? f2bf(W1[k * 512 + n]) : (short)0;
    }
    W1f[id] = o;
  } else if (id < n1 + n2) {
    int t = id - n1;
    int lane = t & 63, nt = (t >> 6) & 15, kb = t >> 10;
    int q = lane >> 4, ln = lane & 15, n = nt * 16 + ln;
    bf16x8 o;
#pragma unroll
    for (int j = 0; j < 8; ++j) {
      int k = kb * 32 + q * 8 + j;  // k < 512 always
      o[j] = f2bf(W2[k * 256 + n]);
    }
    W2f[t] = o;
  } else if (id < n1 + n2 + n3) {
    int t = id - n1 - n2;
    int lane = t & 63, nt = (t >> 6) & 7, kb = t >> 9;
    int q = lane >> 4, ln = lane & 15, n = nt * 16 + ln;
    bf16x8 o;
#pragma unroll
    for (int j = 0; j < 8; ++j) {
      int k = kb * 32 + q * 8 + j;
      o[j] = (k < 266) ? f2bf(Wg[k * 128 + n]) : (short)0;
    }
    Wgf[t] = o;
  }
}

// ---------------- fused 3-stage MLP: y[n] = (comb@Wg) * dinv[n], bf16 out ----
// One wave = 16 nodes. B-frags direct from L1/L2 (fragment-ordered weights).
// h, subj round-trip through wave-private XOR-swizzled LDS (C-layout -> A-layout).
__global__ __launch_bounds__(256, 2) void mlp_k(
    const float* __restrict__ x, const bf16x8* __restrict__ W1f,
    const bf16x8* __restrict__ W2f, const bf16x8* __restrict__ Wgf,
    const float* __restrict__ b1, const float* __restrict__ b2,
    const float* __restrict__ dinv, unsigned short* __restrict__ y) {
  __shared__ __align__(16) short smem[4 * 16 * 512];  // 64 KB
  const int tid = threadIdx.x;
  const int wave = tid >> 6, lane = tid & 63;
  const int q = lane >> 4, ln = lane & 15;
  int base = (blockIdx.x * 4 + wave) * 16;
  if (base > NN - 16) base = NN - 16;  // tail waves recompute last rows (benign dup)
  short* hbuf = smem + wave * (16 * 512);

  const float* xrow = x + (long)(base + ln) * 1010;

  // ---- stage 1: h[16][512] = relu(feats @ W1 + b1) ----
  f32x4 acc1[32];
#pragma unroll
  for (int i = 0; i < 32; ++i) acc1[i] = f32x4{0.f, 0.f, 0.f, 0.f};

  float2 nx0, nx1, nx2, nx3;
  {
    const float2* p = (const float2*)(xrow + q * 8);
    nx0 = p[0]; nx1 = p[1]; nx2 = p[2]; nx3 = p[3];
  }
#pragma unroll 1
  for (int kb = 0; kb < 32; ++kb) {
    float2 c0 = nx0, c1 = nx1, c2 = nx2, c3 = nx3;
    if (kb < 31) {
      int k0n = (kb + 1) * 32 + q * 8;
      if (k0n + 8 <= 1000) {
        const float2* p = (const float2*)(xrow + k0n);
        nx0 = p[0]; nx1 = p[1]; nx2 = p[2]; nx3 = p[3];
      } else {
        nx0 = float2{0.f, 0.f}; nx1 = nx0; nx2 = nx0; nx3 = nx0;
      }
    }
    bf16x8 af;
    af[0] = f2bf(c0.x); af[1] = f2bf(c0.y); af[2] = f2bf(c1.x); af[3] = f2bf(c1.y);
    af[4] = f2bf(c2.x); af[5] = f2bf(c2.y); af[6] = f2bf(c3.x); af[7] = f2bf(c3.y);
    const bf16x8* wp = W1f + (kb * 32) * 64 + lane;
#pragma unroll
    for (int nt = 0; nt < 32; ++nt) {
      bf16x8 bfv = wp[nt * 64];
      acc1[nt] = __builtin_amdgcn_mfma_f32_16x16x32_bf16(af, bfv, acc1[nt], 0, 0, 0);
    }
  }
  // epilogue: relu(+b1) -> hbuf[m][k], XOR-swizzled 16B chunks
#pragma unroll
  for (int nt = 0; nt < 32; ++nt) {
    float bv = b1[nt * 16 + ln];
#pragma unroll
    for (int r = 0; r < 4; ++r) {
      int m = q * 4 + r;
      int cc = nt * 16 + ln;
      float v = fmaxf(acc1[nt][r] + bv, 0.f);
      hbuf[m * 512 + (((cc >> 3) ^ (m & 7)) << 3) + (cc & 7)] = f2bf(v);
    }
  }
  __syncthreads();

  // ---- stage 2: subj[16][256] = h @ W2 + b2 ----
  f32x4 acc2[16];
#pragma unroll
  for (int i = 0; i < 16; ++i) acc2[i] = f32x4{0.f, 0.f, 0.f, 0.f};
#pragma unroll 1
  for (int kb = 0; kb < 16; ++kb) {
    bf16x8 af = *(const bf16x8*)(hbuf + ln * 512 + (((kb * 4 + q) ^ (ln & 7)) << 3));
    const bf16x8* wp = W2f + (kb * 16) * 64 + lane;
#pragma unroll
    for (int nt = 0; nt < 16; ++nt)
      acc2[nt] = __builtin_amdgcn_mfma_f32_16x16x32_bf16(af, wp[nt * 64], acc2[nt], 0, 0, 0);
  }
  __syncthreads();
  short* sbuf = hbuf;  // reuse wave-private region (h fully consumed)
#pragma unroll
  for (int nt = 0; nt < 16; ++nt) {
    float bv = b2[nt * 16 + ln];
#pragma unroll
    for (int r = 0; r < 4; ++r) {
      int m = q * 4 + r;
      int cc = nt * 16 + ln;
      sbuf[m * 256 + (((cc >> 3) ^ (m & 7)) << 3) + (cc & 7)] = f2bf(acc2[nt][r] + bv);
    }
  }
  __syncthreads();

  // ---- stage 3: xt[16][128] = subj @ Wg[0:256] + demo @ Wg[256:266] ----
  f32x4 acc3[8];
#pragma unroll
  for (int i = 0; i < 8; ++i) acc3[i] = f32x4{0.f, 0.f, 0.f, 0.f};
#pragma unroll 1
  for (int kb = 0; kb < 8; ++kb) {
    bf16x8 af = *(const bf16x8*)(sbuf + ln * 256 + (((kb * 4 + q) ^ (ln & 7)) << 3));
    const bf16x8* wp = Wgf + (kb * 8) * 64 + lane;
#pragma unroll
    for (int nt = 0; nt < 8; ++nt)
      acc3[nt] = __builtin_amdgcn_mfma_f32_16x16x32_bf16(af, wp[nt * 64], acc3[nt], 0, 0, 0);
  }
  {  // demo K-block (kb=8): k_local = q*8+j < 10 valid
    bf16x8 af;
#pragma unroll
    for (int j = 0; j < 8; ++j) {
      int kk = q * 8 + j;
      af[j] = (kk < 10) ? f2bf(xrow[1000 + kk]) : (short)0;
    }
    const bf16x8* wp = Wgf + (8 * 8) * 64 + lane;
#pragma unroll
    for (int nt = 0; nt < 8; ++nt)
      acc3[nt] = __builtin_amdgcn_mfma_f32_16x16x32_bf16(af, wp[nt * 64], acc3[nt], 0, 0, 0);
  }
  // epilogue: y[node][c] = bf16(xt * dinv[node])
  float dv[4];
#pragma unroll
  for (int r = 0; r < 4; ++r) dv[r] = dinv[base + q * 4 + r];
#pragma unroll
  for (int nt = 0; nt < 8; ++nt) {
#pragma unroll
    for (int r = 0; r < 4; ++r) {
      int node = base + q * 4 + r;
      y[node * 128 + nt * 16 + ln] = (unsigned short)f2bf(acc3[nt][r] * dv[r]);
    }
  }
}

// ---------------- graph: degree count (edge_index is int32 from harness!) ---
__global__ void deg_k(const int* __restrict__ ei, int* __restrict__ deg) {
  int i = blockIdx.x * 256 + threadIdx.x;
  if (i < NE) {
    unsigned d = (unsigned)ei[NE + i];
    if (d < (unsigned)NN) atomicAdd(&deg[d], 1);  // guard: fail soft, not segv
  }
}

// ---------------- scan: row_ptr (exclusive), cursor copy, dinv ----------------
__global__ void scan_k(const int* __restrict__ deg, int* __restrict__ row_ptr,
                       int* __restrict__ cursor, float* __restrict__ dinv) {
  __shared__ int part[1024];
  int t = threadIdx.x;
  const int CH = 98;  // 1024*98 >= 100000
  int beg = t * CH; if (beg > NN) beg = NN;
  int end = beg + CH; if (end > NN) end = NN;
  int s = 0;
  for (int i = beg; i < end; ++i) s += deg[i];
  part[t] = s;
  __syncthreads();
  int val = s;
  for (int off = 1; off < 1024; off <<= 1) {
    int add = (t >= off) ? part[t - off] : 0;
    __syncthreads();
    val += add;
    part[t] = val;
    __syncthreads();
  }
  int run = val - s;  // exclusive prefix
  for (int i = beg; i < end; ++i) {
    row_ptr[i] = run;
    cursor[i] = run;
    dinv[i] = rsqrtf((float)(deg[i] + 1));  // +1 self-loop -> never zero
    run += deg[i];
  }
  if (t == 1023) row_ptr[NN] = val;  // total = #in-range edges (== NE)
}

// ---------------- CSR fill ----------------
__global__ void fill_k(const int* __restrict__ ei, int* __restrict__ cursor,
                       int* __restrict__ csr) {
  int i = blockIdx.x * 256 + threadIdx.x;
  if (i < NE) {
    unsigned s = (unsigned)ei[i];
    unsigned d = (unsigned)ei[NE + i];
    if (d < (unsigned)NN && s < (unsigned)NN) {
      unsigned pos = (unsigned)atomicAdd(&cursor[d], 1);
      if (pos < (unsigned)NE) csr[pos] = (int)s;  // guard: fail soft
    }
  }
}

// ---------------- aggregate + relu + dot(Wo) per node (1 wave/node) --------
__global__ void agg_k(const unsigned short* __restrict__ y,
                      const int* __restrict__ row_ptr, const int* __restrict__ csr,
                      const float* __restrict__ dinv, const float* __restrict__ bg,
                      const float* __restrict__ Wo, float* __restrict__ c) {
  int n = blockIdx.x;
  int t = threadIdx.x;  // 64; thread owns cols 2t, 2t+1
  unsigned u = ((const unsigned*)(y + n * 128))[t];  // self-loop term
  float a0 = bf2f((unsigned short)(u & 0xFFFF));
  float a1 = bf2f((unsigned short)(u >> 16));
  int e0 = row_ptr[n], e1 = row_ptr[n + 1];
  for (int e = e0; e < e1; ++e) {
    int s = csr[e];
    unsigned v = ((const unsigned*)(y + s * 128))[t];
    a0 += bf2f((unsigned short)(v & 0xFFFF));
    a1 += bf2f((unsigned short)(v >> 16));
  }
  float dn = dinv[n];
  float2 bg2 = ((const float2*)bg)[t];
  float2 wo2 = ((const float2*)Wo)[t];
  float v = fmaxf(a0 * dn + bg2.x, 0.f) * wo2.x + fmaxf(a1 * dn + bg2.y, 0.f) * wo2.y;
  v += __shfl_down(v, 32);
  v += __shfl_down(v, 16);
  v += __shfl_down(v, 8);
  v += __shfl_down(v, 4);
  v += __shfl_down(v, 2);
  v += __shfl_down(v, 1);
  if (t == 0) c[n] = v;
}

// ---------------- final mean + bo ----------------
__global__ void red_k(const float* __restrict__ c, const float* __restrict__ bo,
                      float* __restrict__ out) {
  int t = threadIdx.x;
  float s = 0.f;
  for (int i = t; i < NN; i += 1024) s += c[i];
  s += __shfl_down(s, 32);
  s += __shfl_down(s, 16);
  s += __shfl_down(s, 8);
  s += __shfl_down(s, 4);
  s += __shfl_down(s, 2);
  s += __shfl_down(s, 1);
  __shared__ float red[16];
  if ((t & 63) == 0) red[t >> 6] = s;
  __syncthreads();
  if (t == 0) {
    float tot = 0.f;
    for (int w = 0; w < 16; ++w) tot += red[w];
    out[0] = tot / (float)NN + bo[0];
  }
}

extern "C" void kernel_launch(void* const* d_in, const int* in_sizes, int n_in,
                              void* d_out, int out_size, void* d_ws, size_t ws_size,
                              hipStream_t stream) {
  (void)in_sizes; (void)n_in; (void)out_size; (void)ws_size;
  const float* x  = (const float*)d_in[0];
  const int*   ei = (const int*)d_in[1];  // harness passes integers as int32
  const float* W1 = (const float*)d_in[2];
  const float* b1 = (const float*)d_in[3];
  const float* W2 = (const float*)d_in[4];
  const float* b2 = (const float*)d_in[5];
  const float* Wg = (const float*)d_in[6];
  const float* bg = (const float*)d_in[7];
  const float* Wo = (const float*)d_in[8];
  const float* bo = (const float*)d_in[9];
  float* out = (float*)d_out;

  // workspace plan (~35.4 MB total; y stored as bf16 to halve footprint)
  char* ws = (char*)d_ws;
  size_t off = 0;
  auto alloc = [&](size_t bytes) -> void* {
    void* p = ws + off;
    off = (off + bytes + 255) & ~(size_t)255;
    return p;
  };
  bf16x8* W1f = (bf16x8*)alloc((size_t)32 * 32 * 64 * 16);  // 1 MB
  bf16x8* W2f = (bf16x8*)alloc((size_t)16 * 16 * 64 * 16);  // 256 KB
  bf16x8* Wgf = (bf16x8*)alloc((size_t)9 * 8 * 64 * 16);    // 72 KB
  int*    deg  = (int*)alloc((size_t)NN * 4);
  float*  dinv = (float*)alloc((size_t)NN * 4);
  int*    rowp = (int*)alloc((size_t)(NN + 1) * 4);
  int*    curs = (int*)alloc((size_t)NN * 4);
  float*  carr = (float*)alloc((size_t)NN * 4);
  int*    csr  = (int*)alloc((size_t)NE * 4);               // 6.4 MB
  unsigned short* y = (unsigned short*)alloc((size_t)NN * 128 * 2);  // 25.6 MB

  zero_k<<<(NN + 255) / 256, 256, 0, stream>>>(deg, NN);
  wconv_k<<<338, 256, 0, stream>>>(W1, W2, Wg, W1f, W2f, Wgf);
  deg_k<<<(NE + 255) / 256, 256, 0, stream>>>(ei, deg);
  scan_k<<<1, 1024, 0, stream>>>(deg, rowp, curs, dinv);
  fill_k<<<(NE + 255) / 256, 256, 0, stream>>>(ei, curs, csr);
  mlp_k<<<1563, 256, 0, stream>>>(x, W1f, W2f, Wgf, b1, b2, dinv, y);
  agg_k<<<NN, 64, 0, stream>>>(y, rowp, csr, dinv, bg, Wo, carr);
  red_k<<<1, 1024, 0, stream>>>(carr, bo, out);
}

// Round 4
// 1450.074 us; speedup vs baseline: 1.1741x; 1.1741x over previous
//
#include <hip/hip_runtime.h>
#include <cstdint>

#define NN 100000
#define NE 1600000

typedef __attribute__((ext_vector_type(8))) short bf16x8;
typedef __attribute__((ext_vector_type(4))) float f32x4;

static __device__ __forceinline__ short f2bf(float f) {
  union { float f; unsigned u; } v; v.f = f;
  unsigned r = (v.u + 0x7FFFu + ((v.u >> 16) & 1u)) >> 16;
  return (short)r;
}
static __device__ __forceinline__ float bf2f(unsigned short s) {
  union { unsigned u; float f; } v; v.u = ((unsigned)s) << 16;
  return v.f;
}
// async global->LDS, 16B per lane (dest = wave-uniform base + lane*16)
static __device__ __forceinline__ void gl_lds16(const void* g, void* l) {
  __builtin_amdgcn_global_load_lds(
      (const __attribute__((address_space(1))) void*)g,
      (__attribute__((address_space(3))) void*)l, 16, 0, 0);
}

// ---------------- zero helper ----------------
__global__ void zero_k(int* __restrict__ p, int n) {
  int i = blockIdx.x * 256 + threadIdx.x;
  if (i < n) p[i] = 0;
}

// ---------------- weight pre-convert to MFMA fragment order ----------------
// W1f: [kb<32][nt<32][lane<64][j<8]  K=1024(pad 1000), N=512   (1 MB, 32KB slabs)
// W2f: [kb<16][nt<16][lane][j]       K=512, N=256              (256KB, 16KB slabs)
// Wgf: [kb<9 ][nt<8 ][lane][j]       K=288(pad 266), N=128     (72KB, 8KB slabs)
__global__ void wconv_k(const float* __restrict__ W1, const float* __restrict__ W2,
                        const float* __restrict__ Wg,
                        bf16x8* __restrict__ W1f, bf16x8* __restrict__ W2f,
                        bf16x8* __restrict__ Wgf) {
  int id = blockIdx.x * 256 + threadIdx.x;
  const int n1 = 32 * 32 * 64, n2 = 16 * 16 * 64, n3 = 9 * 8 * 64;
  if (id < n1) {
    int lane = id & 63, nt = (id >> 6) & 31, kb = id >> 11;
    int q = lane >> 4, ln = lane & 15, n = nt * 16 + ln;
    bf16x8 o;
#pragma unroll
    for (int j = 0; j < 8; ++j) {
      int k = kb * 32 + q * 8 + j;
      o[j] = (k < 1000) ? f2bf(W1[k * 512 + n]) : (short)0;
    }
    W1f[id] = o;
  } else if (id < n1 + n2) {
    int t = id - n1;
    int lane = t & 63, nt = (t >> 6) & 15, kb = t >> 10;
    int q = lane >> 4, ln = lane & 15, n = nt * 16 + ln;
    bf16x8 o;
#pragma unroll
    for (int j = 0; j < 8; ++j) {
      int k = kb * 32 + q * 8 + j;
      o[j] = f2bf(W2[k * 256 + n]);
    }
    W2f[t] = o;
  } else if (id < n1 + n2 + n3) {
    int t = id - n1 - n2;
    int lane = t & 63, nt = (t >> 6) & 7, kb = t >> 9;
    int q = lane >> 4, ln = lane & 15, n = nt * 16 + ln;
    bf16x8 o;
#pragma unroll
    for (int j = 0; j < 8; ++j) {
      int k = kb * 32 + q * 8 + j;
      o[j] = (k < 266) ? f2bf(Wg[k * 128 + n]) : (short)0;
    }
    Wgf[t] = o;
  }
}

// ---------------- fused 3-stage MLP ----------------
// Block: 512 thr = 8 waves (wr<2, wc<4); tile 128 rows x 512 cols.
// Wave: 64 rows x 128 cols = 4 M-tiles x 8 nt (acc 128 regs).
// Stage1: A (x rows, bf16) + B (W1f slab) staged in LDS per kb.
// Stage2/3: h/subj go through chunked LDS transform; W2f/Wgf slabs LDS-staged.
__global__ __launch_bounds__(512, 2) void mlp_k(
    const float* __restrict__ x, const bf16x8* __restrict__ W1f,
    const bf16x8* __restrict__ W2f, const bf16x8* __restrict__ Wgf,
    const float* __restrict__ b1, const float* __restrict__ b2,
    const float* __restrict__ dinv, unsigned short* __restrict__ y) {
  __shared__ __align__(16) short smem[32768];  // 64 KB
  const int tid = threadIdx.x;
  const int wave = tid >> 6, lane = tid & 63;
  const int q = lane >> 4, ln = lane & 15;
  const int wr = wave >> 2, wc = wave & 3;
  int rb = blockIdx.x * 128;
  if (rb > NN - 128) rb = NN - 128;  // tail overlap: duplicate identical work

  // ---- stage 1: h = relu(x[:, :1000] @ W1 + b1), kept in acc1 ----
  f32x4 acc1[4][8];
#pragma unroll
  for (int a = 0; a < 4; ++a)
#pragma unroll
    for (int b = 0; b < 8; ++b) acc1[a][b] = f32x4{0.f, 0.f, 0.f, 0.f};

  const int arow = tid >> 2;        // 0..127 (staging row)
  const int akc = (tid & 3) * 8;    // k-chunk within kb
  const float* xr = x + (size_t)(rb + arow) * 1010;
  short* Abuf = smem;               // 128 rows x 40 shorts (80B padded)
  short* Bbuf = smem + 6144;        // 16384 shorts = 32KB slab

  float2 p0, p1, p2, p3;
  { const float2* p = (const float2*)(xr + akc); p0 = p[0]; p1 = p[1]; p2 = p[2]; p3 = p[3]; }

#pragma unroll 1
  for (int kb = 0; kb < 32; ++kb) {
    __syncthreads();  // A/B buffers free
    {
      bf16x8 av;
      av[0] = f2bf(p0.x); av[1] = f2bf(p0.y); av[2] = f2bf(p1.x); av[3] = f2bf(p1.y);
      av[4] = f2bf(p2.x); av[5] = f2bf(p2.y); av[6] = f2bf(p3.x); av[7] = f2bf(p3.y);
      *(bf16x8*)(Abuf + arow * 40 + akc) = av;
    }
    {
      const char* gB = (const char*)W1f + (size_t)kb * 32768;
      char* lB = (char*)Bbuf;
#pragma unroll
      for (int i = 0; i < 4; ++i)
        gl_lds16(gB + (i * 512 + tid) * 16, lB + (i * 512 + tid) * 16);
    }
    if (kb < 31) {
      int gk = (kb + 1) * 32 + akc;
      if (gk + 8 <= 1000) {
        const float2* p = (const float2*)(xr + gk);
        p0 = p[0]; p1 = p[1]; p2 = p[2]; p3 = p[3];
      } else {
        p0 = float2{0.f, 0.f}; p1 = p0; p2 = p0; p3 = p0;
      }
    }
    __syncthreads();  // A writes visible + B slab arrived
    bf16x8 af[4];
#pragma unroll
    for (int mt = 0; mt < 4; ++mt)
      af[mt] = *(const bf16x8*)(Abuf + (wr * 64 + mt * 16 + ln) * 40 + q * 8);
#pragma unroll
    for (int i = 0; i < 8; ++i) {
      bf16x8 bfv = *(const bf16x8*)(Bbuf + ((wc * 8 + i) * 64 + lane) * 8);
#pragma unroll
      for (int mt = 0; mt < 4; ++mt)
        acc1[mt][i] = __builtin_amdgcn_mfma_f32_16x16x32_bf16(af[mt], bfv, acc1[mt][i], 0, 0, 0);
    }
  }

  // ---- stage 2: subj = h @ W2 + b2 (chunked h transform through LDS) ----
  f32x4 acc2[4][4];
#pragma unroll
  for (int a = 0; a < 4; ++a)
#pragma unroll
    for (int b = 0; b < 4; ++b) acc2[a][b] = f32x4{0.f, 0.f, 0.f, 0.f};
  short* H = smem;            // 128 rows x 128 shorts (swizzled 16B granules)
  short* Wr = smem + 16384;   // weight slab region

#pragma unroll 1
  for (int c = 0; c < 4; ++c) {
    __syncthreads();  // H free (prev chunk consumed)
    if (wc == c) {    // writers: waves (wr, c) -> h cols c*128..+128
#pragma unroll
      for (int mt = 0; mt < 4; ++mt)
#pragma unroll
        for (int i = 0; i < 8; ++i) {
          float bv = b1[c * 128 + i * 16 + ln];
#pragma unroll
          for (int r = 0; r < 4; ++r) {
            int rl = wr * 64 + mt * 16 + q * 4 + r;
            int cc = i * 16 + ln;
            float v = fmaxf(acc1[mt][i][r] + bv, 0.f);
            H[rl * 128 + (((cc >> 3) ^ (rl & 7)) << 3) + (cc & 7)] = f2bf(v);
          }
        }
    }
    __syncthreads();  // H chunk ready
#pragma unroll 1
    for (int k2 = 0; k2 < 4; ++k2) {
      int kb2 = c * 4 + k2;
      const char* gW = (const char*)W2f + (size_t)kb2 * 16384;
#pragma unroll
      for (int i = 0; i < 2; ++i)
        gl_lds16(gW + (i * 512 + tid) * 16, (char*)Wr + (i * 512 + tid) * 16);
      __syncthreads();  // slab ready
      bf16x8 af[4];
#pragma unroll
      for (int mt = 0; mt < 4; ++mt) {
        int rl = wr * 64 + mt * 16 + ln;
        af[mt] = *(const bf16x8*)(H + rl * 128 + (((k2 * 4 + q) ^ (rl & 7)) << 3));
      }
#pragma unroll
      for (int i = 0; i < 4; ++i) {
        bf16x8 bfv = *(const bf16x8*)(Wr + ((wc * 4 + i) * 64 + lane) * 8);
#pragma unroll
        for (int mt = 0; mt < 4; ++mt)
          acc2[mt][i] = __builtin_amdgcn_mfma_f32_16x16x32_bf16(af[mt], bfv, acc2[mt][i], 0, 0, 0);
      }
      __syncthreads();  // slab free
    }
  }

  // ---- stage 3: xt = subj @ Wg[0:256] + demo @ Wg[256:266] ----
  f32x4 acc3[4][2];
#pragma unroll
  for (int a = 0; a < 4; ++a)
#pragma unroll
    for (int b = 0; b < 2; ++b) acc3[a][b] = f32x4{0.f, 0.f, 0.f, 0.f};

#pragma unroll 1
  for (int c3 = 0; c3 < 2; ++c3) {
    __syncthreads();
    if ((wc >> 1) == c3) {  // writers: 4 waves -> subj cols c3*128..+128
#pragma unroll
      for (int mt = 0; mt < 4; ++mt)
#pragma unroll
        for (int i = 0; i < 4; ++i) {
          float bv = b2[wc * 64 + i * 16 + ln];
#pragma unroll
          for (int r = 0; r < 4; ++r) {
            int rl = wr * 64 + mt * 16 + q * 4 + r;
            int cc = (wc & 1) * 64 + i * 16 + ln;
            H[rl * 128 + (((cc >> 3) ^ (rl & 7)) << 3) + (cc & 7)] = f2bf(acc2[mt][i][r] + bv);
          }
        }
    }
    __syncthreads();
#pragma unroll 1
    for (int k3 = 0; k3 < 4; ++k3) {
      int kb3 = c3 * 4 + k3;
      gl_lds16((const char*)Wgf + (size_t)kb3 * 8192 + tid * 16, (char*)Wr + tid * 16);
      __syncthreads();
      bf16x8 af[4];
#pragma unroll
      for (int mt = 0; mt < 4; ++mt) {
        int rl = wr * 64 + mt * 16 + ln;
        af[mt] = *(const bf16x8*)(H + rl * 128 + (((k3 * 4 + q) ^ (rl & 7)) << 3));
      }
#pragma unroll
      for (int i = 0; i < 2; ++i) {
        bf16x8 bfv = *(const bf16x8*)(Wr + ((wc * 2 + i) * 64 + lane) * 8);
#pragma unroll
        for (int mt = 0; mt < 4; ++mt)
          acc3[mt][i] = __builtin_amdgcn_mfma_f32_16x16x32_bf16(af[mt], bfv, acc3[mt][i], 0, 0, 0);
      }
      __syncthreads();
    }
  }
  {  // demo K-block (kb3 = 8): A from x demo cols directly
    gl_lds16((const char*)Wgf + (size_t)8 * 8192 + tid * 16, (char*)Wr + tid * 16);
    __syncthreads();
    bf16x8 af[4];
#pragma unroll
    for (int mt = 0; mt < 4; ++mt) {
      const float* xr2 = x + (size_t)(rb + wr * 64 + mt * 16 + ln) * 1010 + 1000;
      bf16x8 a;
#pragma unroll
      for (int j = 0; j < 8; ++j) {
        int kk = q * 8 + j;
        a[j] = (kk < 10) ? f2bf(xr2[kk]) : (short)0;
      }
      af[mt] = a;
    }
#pragma unroll
    for (int i = 0; i < 2; ++i) {
      bf16x8 bfv = *(const bf16x8*)(Wr + ((wc * 2 + i) * 64 + lane) * 8);
#pragma unroll
      for (int mt = 0; mt < 4; ++mt)
        acc3[mt][i] = __builtin_amdgcn_mfma_f32_16x16x32_bf16(af[mt], bfv, acc3[mt][i], 0, 0, 0);
    }
  }

  // ---- epilogue: y[node][col] = bf16(xt * dinv[node]) ----
#pragma unroll
  for (int mt = 0; mt < 4; ++mt) {
    float dv[4];
#pragma unroll
    for (int r = 0; r < 4; ++r) dv[r] = dinv[rb + wr * 64 + mt * 16 + q * 4 + r];
#pragma unroll
    for (int i = 0; i < 2; ++i)
#pragma unroll
      for (int r = 0; r < 4; ++r) {
        int node = rb + wr * 64 + mt * 16 + q * 4 + r;
        y[(size_t)node * 128 + wc * 32 + i * 16 + ln] =
            (unsigned short)f2bf(acc3[mt][i][r] * dv[r]);
      }
  }
}

// ---------------- graph: degree count (edge_index arrives as int32) --------
__global__ void deg_k(const int* __restrict__ ei, int* __restrict__ deg) {
  int i = blockIdx.x * 256 + threadIdx.x;
  if (i < NE) {
    unsigned d = (unsigned)ei[NE + i];
    if (d < (unsigned)NN) atomicAdd(&deg[d], 1);
  }
}

// ---------------- 3-phase parallel scan (100 blocks x 1000 nodes) ----------
__global__ void sc1_k(const int* __restrict__ deg, int* __restrict__ btot) {
  __shared__ int red[4];
  int b = blockIdx.x, t = threadIdx.x;
  int s = 0;
  for (int i = t; i < 1000; i += 256) s += deg[b * 1000 + i];
  s += __shfl_down(s, 32); s += __shfl_down(s, 16); s += __shfl_down(s, 8);
  s += __shfl_down(s, 4);  s += __shfl_down(s, 2);  s += __shfl_down(s, 1);
  if ((t & 63) == 0) red[t >> 6] = s;
  __syncthreads();
  if (t == 0) btot[b] = red[0] + red[1] + red[2] + red[3];
}

__global__ void sc2_k(const int* __restrict__ btot, int* __restrict__ boff,
                      int* __restrict__ row_ptr) {
  __shared__ int wt[2];
  int t = threadIdx.x;  // 128
  int xv = (t < 100) ? btot[t] : 0;
  int inc = xv;
  for (int d = 1; d < 64; d <<= 1) {
    int o = __shfl_up(inc, d);
    if ((t & 63) >= d) inc += o;
  }
  if ((t & 63) == 63) wt[t >> 6] = inc;
  __syncthreads();
  if (t >= 64) inc += wt[0];
  if (t < 100) boff[t] = inc - xv;
  if (t == 99) row_ptr[NN] = inc;
}

__global__ void sc3_k(const int* __restrict__ deg, const int* __restrict__ boff,
                      int* __restrict__ row_ptr, int* __restrict__ cursor,
                      float* __restrict__ dinv) {
  __shared__ int part[256];
  int b = blockIdx.x, t = threadIdx.x;
  int i0 = t * 4;
  int d[4]; int s = 0;
#pragma unroll
  for (int j = 0; j < 4; ++j) {
    int i = i0 + j;
    d[j] = (i < 1000) ? deg[b * 1000 + i] : 0;
    s += d[j];
  }
  part[t] = s;
  __syncthreads();
  int val = s;
  for (int off = 1; off < 256; off <<= 1) {
    int add = (t >= off) ? part[t - off] : 0;
    __syncthreads();
    val += add;
    part[t] = val;
    __syncthreads();
  }
  int run = boff[b] + val - s;
#pragma unroll
  for (int j = 0; j < 4; ++j) {
    int i = i0 + j;
    if (i < 1000) {
      int node = b * 1000 + i;
      row_ptr[node] = run;
      cursor[node] = run;
      dinv[node] = rsqrtf((float)(d[j] + 1));
      run += d[j];
    }
  }
}

// ---------------- CSR fill ----------------
__global__ void fill_k(const int* __restrict__ ei, int* __restrict__ cursor,
                       int* __restrict__ csr) {
  int i = blockIdx.x * 256 + threadIdx.x;
  if (i < NE) {
    unsigned s = (unsigned)ei[i];
    unsigned d = (unsigned)ei[NE + i];
    if (d < (unsigned)NN && s < (unsigned)NN) {
      unsigned pos = (unsigned)atomicAdd(&cursor[d], 1);
      if (pos < (unsigned)NE) csr[pos] = (int)s;
    }
  }
}

// -------- aggregate + relu + dot(Wo) per node (1 wave/node, 4 nodes/block) --
__global__ void agg_k(const unsigned short* __restrict__ y,
                      const int* __restrict__ row_ptr, const int* __restrict__ csr,
                      const float* __restrict__ dinv, const float* __restrict__ bg,
                      const float* __restrict__ Wo, float* __restrict__ c) {
  int w = threadIdx.x >> 6, l = threadIdx.x & 63;
  int n = blockIdx.x * 4 + w;  // NN = 25000*4 exact
  unsigned u = ((const unsigned*)(y + (size_t)n * 128))[l];  // self-loop
  float a0 = bf2f((unsigned short)(u & 0xFFFF));
  float a1 = bf2f((unsigned short)(u >> 16));
  int e0 = row_ptr[n], e1 = row_ptr[n + 1];
  for (int e = e0; e < e1; e += 64) {
    int sv = (e + l < e1) ? csr[e + l] : 0;  // lane-parallel prefetch
    int m = e1 - e; if (m > 64) m = 64;
    for (int j = 0; j < m; ++j) {
      int s = __shfl(sv, j);
      unsigned v = ((const unsigned*)(y + (size_t)s * 128))[l];
      a0 += bf2f((unsigned short)(v & 0xFFFF));
      a1 += bf2f((unsigned short)(v >> 16));
    }
  }
  float dn = dinv[n];
  float2 bg2 = ((const float2*)bg)[l];
  float2 wo2 = ((const float2*)Wo)[l];
  float v = fmaxf(a0 * dn + bg2.x, 0.f) * wo2.x + fmaxf(a1 * dn + bg2.y, 0.f) * wo2.y;
  v += __shfl_down(v, 32); v += __shfl_down(v, 16); v += __shfl_down(v, 8);
  v += __shfl_down(v, 4);  v += __shfl_down(v, 2);  v += __shfl_down(v, 1);
  if (l == 0) c[n] = v;
}

// ---------------- final mean + bo ----------------
__global__ void red_k(const float* __restrict__ c, const float* __restrict__ bo,
                      float* __restrict__ out) {
  int t = threadIdx.x;
  float s = 0.f;
  for (int i = t; i < NN; i += 1024) s += c[i];
  s += __shfl_down(s, 32); s += __shfl_down(s, 16); s += __shfl_down(s, 8);
  s += __shfl_down(s, 4);  s += __shfl_down(s, 2);  s += __shfl_down(s, 1);
  __shared__ float red[16];
  if ((t & 63) == 0) red[t >> 6] = s;
  __syncthreads();
  if (t == 0) {
    float tot = 0.f;
    for (int w = 0; w < 16; ++w) tot += red[w];
    out[0] = tot / (float)NN + bo[0];
  }
}

extern "C" void kernel_launch(void* const* d_in, const int* in_sizes, int n_in,
                              void* d_out, int out_size, void* d_ws, size_t ws_size,
                              hipStream_t stream) {
  (void)in_sizes; (void)n_in; (void)out_size; (void)ws_size;
  const float* x  = (const float*)d_in[0];
  const int*   ei = (const int*)d_in[1];  // int32 from harness
  const float* W1 = (const float*)d_in[2];
  const float* b1 = (const float*)d_in[3];
  const float* W2 = (const float*)d_in[4];
  const float* b2 = (const float*)d_in[5];
  const float* Wg = (const float*)d_in[6];
  const float* bg = (const float*)d_in[7];
  const float* Wo = (const float*)d_in[8];
  const float* bo = (const float*)d_in[9];
  float* out = (float*)d_out;

  char* ws = (char*)d_ws;
  size_t off = 0;
  auto alloc = [&](size_t bytes) -> void* {
    void* p = ws + off;
    off = (off + bytes + 255) & ~(size_t)255;
    return p;
  };
  bf16x8* W1f = (bf16x8*)alloc((size_t)32 * 32 * 64 * 16);  // 1 MB
  bf16x8* W2f = (bf16x8*)alloc((size_t)16 * 16 * 64 * 16);  // 256 KB
  bf16x8* Wgf = (bf16x8*)alloc((size_t)9 * 8 * 64 * 16);    // 72 KB
  int*    deg  = (int*)alloc((size_t)NN * 4);
  float*  dinv = (float*)alloc((size_t)NN * 4);
  int*    rowp = (int*)alloc((size_t)(NN + 1) * 4);
  int*    curs = (int*)alloc((size_t)NN * 4);
  float*  carr = (float*)alloc((size_t)NN * 4);
  int*    btot = (int*)alloc((size_t)128 * 4);
  int*    boff = (int*)alloc((size_t)128 * 4);
  int*    csr  = (int*)alloc((size_t)NE * 4);               // 6.4 MB
  unsigned short* y = (unsigned short*)alloc((size_t)NN * 128 * 2);  // 25.6 MB

  zero_k<<<(NN + 255) / 256, 256, 0, stream>>>(deg, NN);
  wconv_k<<<338, 256, 0, stream>>>(W1, W2, Wg, W1f, W2f, Wgf);
  deg_k<<<(NE + 255) / 256, 256, 0, stream>>>(ei, deg);
  sc1_k<<<100, 256, 0, stream>>>(deg, btot);
  sc2_k<<<1, 128, 0, stream>>>(btot, boff, rowp);
  sc3_k<<<100, 256, 0, stream>>>(deg, boff, rowp, curs, dinv);
  fill_k<<<(NE + 255) / 256, 256, 0, stream>>>(ei, curs, csr);
  mlp_k<<<782, 512, 0, stream>>>(x, W1f, W2f, Wgf, b1, b2, dinv, y);
  agg_k<<<25000, 256, 0, stream>>>(y, rowp, csr, dinv, bg, Wo, carr);
  red_k<<<1, 1024, 0, stream>>>(carr, bo, out);
}